// Round 1
// baseline (6941.119 us; speedup 1.0000x reference)
//
#include <hip/hip_runtime.h>

#define BB 64
#define TT 512
#define HH 1024
#define OUTN 32000
#define NG 32           // persistent workgroups
#define NW 32           // output columns per WG (HH/NG)
#define NTHREADS 256

typedef __attribute__((ext_vector_type(8))) short s16x8;
typedef __attribute__((ext_vector_type(4))) float f32x4;
typedef __attribute__((ext_vector_type(4))) int i32x4;

static __device__ __forceinline__ unsigned short f2bf(float f) {
  union { float f; unsigned u; } a; a.f = f;
  unsigned r = a.u + 0x7fffu + ((a.u >> 16) & 1u);   // RNE
  return (unsigned short)(r >> 16);
}

// Persistent RNN kernel: 32 WGs, WG g owns output columns [g*32, g*32+32).
// Whh^T slice lives in LDS in MFMA B-fragment order for the whole kernel.
__global__ __launch_bounds__(NTHREADS) void rnn_persist(
    const int* __restrict__ x, const float* __restrict__ Wxh,
    const float* __restrict__ Whh_w, const float* __restrict__ Whh_b,
    unsigned* __restrict__ ctr, unsigned short* __restrict__ hbuf) {
  const int g = blockIdx.x;
  const int tid = threadIdx.x;
  const int w = tid >> 6;        // wave 0..3 -> batch rows [16w,16w+16)
  const int l = tid & 63;
  const int lr = l & 15;
  const int lq = l >> 4;
  const int jbase = g * NW;
  const int rowbase = w * 16;

  // [kb 0..31][nt 0..1][lane 0..63][8 bf16] = 64 KB
  __shared__ __align__(16) unsigned short wlds[32 * 2 * 64 * 8];

  // One-time pack: B[k][col] = Whh_w[col][k], fragment order:
  // lane ln supplies k = kb*32 + (ln>>4)*8 + j, col = jbase + nt*16 + (ln&15)
  for (int e = tid; e < 32 * 2 * 64; e += NTHREADS) {
    int kb = e >> 7;
    int nt = (e >> 6) & 1;
    int ln = e & 63;
    int col = jbase + nt * 16 + (ln & 15);
    int k0 = kb * 32 + (ln >> 4) * 8;
    const float* src = Whh_w + (size_t)col * HH + k0;
    union { unsigned short u[8]; i32x4 v; } pk;
    #pragma unroll
    for (int j = 0; j < 8; ++j) pk.u[j] = f2bf(src[j]);
    *reinterpret_cast<i32x4*>(&wlds[(size_t)e * 8]) = pk.v;
  }
  const float bias0 = Whh_b[jbase + lr];
  const float bias1 = Whh_b[jbase + 16 + lr];
  __syncthreads();

  for (int s = 0; s < TT; ++s) {
    const unsigned short* hprev = hbuf + (size_t)(s & 1) * (BB * HH);
    unsigned short* hcur = hbuf + (size_t)((s + 1) & 1) * (BB * HH);

    // Embedding gather for this step — independent of h, issue before K-loop
    float e0v[4], e1v[4];
    #pragma unroll
    for (int i = 0; i < 4; ++i) {
      int b = rowbase + lq * 4 + i;
      int xi = x[b * TT + s];
      const float* er = Wxh + (size_t)xi * HH + jbase;
      e0v[i] = er[lr];
      e1v[i] = er[16 + lr];
    }

    f32x4 acc0 = {0.f, 0.f, 0.f, 0.f};
    f32x4 acc1 = {0.f, 0.f, 0.f, 0.f};
    // A-frag: lane l -> row rowbase+(l&15), k = kb*32 + (l>>4)*8 + [0..8)
    const unsigned short* aptr = hprev + (size_t)(rowbase + lr) * HH + lq * 8;
    #pragma unroll 8
    for (int kb = 0; kb < 32; ++kb) {
      s16x8 a = *reinterpret_cast<const s16x8*>(aptr + kb * 32);
      s16x8 b0 = *reinterpret_cast<const s16x8*>(&wlds[((kb * 2 + 0) * 64 + l) * 8]);
      s16x8 b1 = *reinterpret_cast<const s16x8*>(&wlds[((kb * 2 + 1) * 64 + l) * 8]);
      acc0 = __builtin_amdgcn_mfma_f32_16x16x32_bf16(a, b0, acc0, 0, 0, 0);
      acc1 = __builtin_amdgcn_mfma_f32_16x16x32_bf16(a, b1, acc1, 0, 0, 0);
    }

    // Epilogue: C/D layout col = lane&15, row = (lane>>4)*4 + reg (m89-verified)
    #pragma unroll
    for (int i = 0; i < 4; ++i) {
      int b = rowbase + lq * 4 + i;
      float v0 = tanhf(acc0[i] + e0v[i] + bias0);
      float v1 = tanhf(acc1[i] + e1v[i] + bias1);
      unsigned short* hc = hcur + (size_t)b * HH + jbase;
      hc[lr] = f2bf(v0);
      hc[16 + lr] = f2bf(v1);
    }

    // Cross-WG barrier: release (wb L2 -> L3), count, acquire (inv L1/L2)
    __threadfence();
    __syncthreads();
    if (tid == 0) {
      __hip_atomic_fetch_add(&ctr[s], 1u, __ATOMIC_RELAXED, __HIP_MEMORY_SCOPE_AGENT);
      int guard = 0;
      while (__hip_atomic_load(&ctr[s], __ATOMIC_RELAXED, __HIP_MEMORY_SCOPE_AGENT)
             < (unsigned)NG) {
        __builtin_amdgcn_s_sleep(2);
        if (++guard > (1 << 22)) break;   // safety valve: never hard-wedge
      }
    }
    __syncthreads();
    __threadfence();
  }
}

// out[64][32000] = h_final @ Why^T + Why_b.  250 WGs x [64 x 128] tile.
__global__ __launch_bounds__(NTHREADS) void rnn_proj(
    const unsigned short* __restrict__ hfin, const float* __restrict__ Why_w,
    const float* __restrict__ Why_b, float* __restrict__ out) {
  const int tid = threadIdx.x;
  const int w = tid >> 6;
  const int l = tid & 63;
  const int lr = l & 15;
  const int lq = l >> 4;
  const int nbase = blockIdx.x * 128;
  const int rowbase = w * 16;

  f32x4 acc[8];
  #pragma unroll
  for (int nt = 0; nt < 8; ++nt) acc[nt] = (f32x4){0.f, 0.f, 0.f, 0.f};

  const unsigned short* aptr = hfin + (size_t)(rowbase + lr) * HH + lq * 8;
  for (int kb = 0; kb < 32; ++kb) {
    s16x8 a = *reinterpret_cast<const s16x8*>(aptr + kb * 32);
    #pragma unroll
    for (int nt = 0; nt < 8; ++nt) {
      int n = nbase + nt * 16 + lr;
      const float* wp = Why_w + (size_t)n * HH + kb * 32 + lq * 8;
      union { unsigned short u[8]; s16x8 v; } bb;
      #pragma unroll
      for (int j = 0; j < 8; ++j) bb.u[j] = f2bf(wp[j]);
      acc[nt] = __builtin_amdgcn_mfma_f32_16x16x32_bf16(a, bb.v, acc[nt], 0, 0, 0);
    }
  }
  #pragma unroll
  for (int nt = 0; nt < 8; ++nt) {
    int n = nbase + nt * 16 + lr;
    float bv = Why_b[n];
    #pragma unroll
    for (int i = 0; i < 4; ++i) {
      int b = rowbase + lq * 4 + i;
      out[(size_t)b * OUTN + n] = acc[nt][i] + bv;
    }
  }
}

extern "C" void kernel_launch(void* const* d_in, const int* in_sizes, int n_in,
                              void* d_out, int out_size, void* d_ws, size_t ws_size,
                              hipStream_t stream) {
  const int* x = (const int*)d_in[0];
  const float* Wxh = (const float*)d_in[1];
  const float* Whh_w = (const float*)d_in[2];
  const float* Whh_b = (const float*)d_in[3];
  const float* Why_w = (const float*)d_in[4];
  const float* Why_b = (const float*)d_in[5];
  float* out = (float*)d_out;

  unsigned* ctr = (unsigned*)d_ws;                                   // 4 KB: step counters
  unsigned short* hbuf = (unsigned short*)((char*)d_ws + 4096);      // 2 x 64 x 1024 bf16

  // zero counters + h0 (and the other h buffer) each call — deterministic
  hipMemsetAsync(d_ws, 0, 4096 + 2 * BB * HH * sizeof(unsigned short), stream);
  rnn_persist<<<NG, NTHREADS, 0, stream>>>(x, Wxh, Whh_w, Whh_b, ctr, hbuf);
  rnn_proj<<<OUTN / 128, NTHREADS, 0, stream>>>(hbuf, Why_w, Why_b, out);
}

// Round 2
// 3734.679 us; speedup vs baseline: 1.8586x; 1.8586x over previous
//
#include <hip/hip_runtime.h>

#define BB 64
#define TT 512
#define HH 1024
#define OUTN 32000
#define NG 32           // persistent workgroups
#define NW 32           // output columns per WG (HH/NG)
#define NTHREADS 256

typedef __attribute__((ext_vector_type(8))) short s16x8;
typedef __attribute__((ext_vector_type(4))) float f32x4;
typedef __attribute__((ext_vector_type(4))) int i32x4;

static __device__ __forceinline__ unsigned short f2bf(float f) {
  union { float f; unsigned u; } a; a.f = f;
  unsigned r = a.u + 0x7fffu + ((a.u >> 16) & 1u);   // RNE
  return (unsigned short)(r >> 16);
}

// tanh via single v_exp_f32: tanh(x) = 1 - 2/(e^{2x}+1); saturates correctly at +-inf
static __device__ __forceinline__ float ftanh(float x) {
  float e = __expf(2.0f * x);
  return 1.0f - 2.0f * __builtin_amdgcn_rcpf(e + 1.0f);
}

// Persistent RNN: 32 WGs, WG g owns output columns [g*32, g*32+32).
// Cross-WG h exchange via sc0 sc1 (coherent-point) loads/stores + per-WG flags.
// NO __threadfence (no L2 writeback/invalidate) anywhere in the loop.
__global__ __launch_bounds__(NTHREADS, 1) void rnn_persist(
    const int* __restrict__ x, const float* __restrict__ Wxh,
    const float* __restrict__ Whh_w, const float* __restrict__ Whh_b,
    unsigned* __restrict__ flags, unsigned short* __restrict__ hbuf) {
  const int g = blockIdx.x;
  const int tid = threadIdx.x;
  const int w = tid >> 6;        // wave 0..3 -> batch rows [16w,16w+16)
  const int l = tid & 63;
  const int lr = l & 15;
  const int lq = l >> 4;
  const int jbase = g * NW;
  const int rowbase = w * 16;

  // [kb 0..31][nt 0..1][lane 0..63][8 bf16] = 64 KB, MFMA B-fragment order
  __shared__ __align__(16) unsigned short wlds[32 * 2 * 64 * 8];

  for (int e = tid; e < 32 * 2 * 64; e += NTHREADS) {
    int kb = e >> 7;
    int nt = (e >> 6) & 1;
    int ln = e & 63;
    int col = jbase + nt * 16 + (ln & 15);
    int k0 = kb * 32 + (ln >> 4) * 8;
    const float* src = Whh_w + (size_t)col * HH + k0;
    union { unsigned short u[8]; i32x4 v; } pk;
    #pragma unroll
    for (int j = 0; j < 8; ++j) pk.u[j] = f2bf(src[j]);
    *reinterpret_cast<i32x4*>(&wlds[(size_t)e * 8]) = pk.v;
  }
  const float bias0 = Whh_b[jbase + lr];
  const float bias1 = Whh_b[jbase + 16 + lr];
  __syncthreads();

  for (int s = 0; s < TT; ++s) {
    const unsigned short* hprev = hbuf + (size_t)(s & 1) * (BB * HH);
    unsigned short* hcur = hbuf + (size_t)((s + 1) & 1) * (BB * HH);

    // Embedding gather — h-independent, plain cached loads, issue BEFORE spin
    float e0v[4], e1v[4];
    #pragma unroll
    for (int i = 0; i < 4; ++i) {
      int b = rowbase + lq * 4 + i;
      int xi = x[b * TT + s];
      const float* er = Wxh + (size_t)xi * HH + jbase;
      e0v[i] = er[lr];
      e1v[i] = er[16 + lr];
    }

    // Wait for all 32 flags of step s-1 (one coalesced 128B poll per iter)
    if (s > 0) {
      const unsigned* fp = flags + (size_t)(s - 1) * NG + (l & 31);
      int guard = 0;
      unsigned fv;
      do {
        asm volatile("global_load_dword %0, %1, off sc0 sc1\n\t"
                     "s_waitcnt vmcnt(0)"
                     : "=v"(fv) : "v"(fp) : "memory");
        if (++guard > (1 << 15)) break;  // safety valve: never hard-wedge
      } while (!__all(fv != 0));
      __builtin_amdgcn_sched_barrier(0);
    }

    // A-fragments: 32 x 16B coherent loads, all in flight, single drain
    i32x4 areg[32];
    const unsigned short* aptr = hprev + (size_t)(rowbase + lr) * HH + lq * 8;
    #pragma unroll
    for (int kb = 0; kb < 32; ++kb)
      asm volatile("global_load_dwordx4 %0, %1, off offset:%2 sc0 sc1"
                   : "=v"(areg[kb]) : "v"(aptr), "i"(kb * 64) : "memory");
    asm volatile("s_waitcnt vmcnt(0)" ::: "memory");
    __builtin_amdgcn_sched_barrier(0);

    // 64 MFMA, 4 independent accumulator chains
    f32x4 acc0a = {0.f, 0.f, 0.f, 0.f}, acc0b = acc0a;
    f32x4 acc1a = acc0a, acc1b = acc0a;
    #pragma unroll
    for (int kb = 0; kb < 32; kb += 2) {
      union { i32x4 i; s16x8 s; } a0, a1;
      a0.i = areg[kb]; a1.i = areg[kb + 1];
      s16x8 b00 = *reinterpret_cast<const s16x8*>(&wlds[(((kb + 0) * 2 + 0) * 64 + l) * 8]);
      s16x8 b01 = *reinterpret_cast<const s16x8*>(&wlds[(((kb + 0) * 2 + 1) * 64 + l) * 8]);
      s16x8 b10 = *reinterpret_cast<const s16x8*>(&wlds[(((kb + 1) * 2 + 0) * 64 + l) * 8]);
      s16x8 b11 = *reinterpret_cast<const s16x8*>(&wlds[(((kb + 1) * 2 + 1) * 64 + l) * 8]);
      acc0a = __builtin_amdgcn_mfma_f32_16x16x32_bf16(a0.s, b00, acc0a, 0, 0, 0);
      acc1a = __builtin_amdgcn_mfma_f32_16x16x32_bf16(a0.s, b01, acc1a, 0, 0, 0);
      acc0b = __builtin_amdgcn_mfma_f32_16x16x32_bf16(a1.s, b10, acc0b, 0, 0, 0);
      acc1b = __builtin_amdgcn_mfma_f32_16x16x32_bf16(a1.s, b11, acc1b, 0, 0, 0);
    }
    f32x4 acc0 = acc0a + acc0b;
    f32x4 acc1 = acc1a + acc1b;

    // Epilogue: C/D col = lane&15, row = (lane>>4)*4 + i; coherent 2B stores
    #pragma unroll
    for (int i = 0; i < 4; ++i) {
      int b = rowbase + lq * 4 + i;
      unsigned v0 = f2bf(ftanh(acc0[i] + e0v[i] + bias0));
      unsigned v1 = f2bf(ftanh(acc1[i] + e1v[i] + bias1));
      unsigned short* hc = hcur + (size_t)b * HH + jbase + lr;
      asm volatile("global_store_short %0, %1, off sc0 sc1" :: "v"(hc), "v"(v0) : "memory");
      asm volatile("global_store_short %0, %1, off offset:32 sc0 sc1" :: "v"(hc), "v"(v1) : "memory");
    }
    asm volatile("s_waitcnt vmcnt(0)" ::: "memory");  // per-wave drain before barrier
    __syncthreads();                                   // whole WG's slice is at L3
    if (tid == 0) {
      unsigned one = 1u;
      asm volatile("global_store_dword %0, %1, off sc0 sc1"
                   :: "v"(flags + (size_t)s * NG + g), "v"(one) : "memory");
    }
  }
}

// out[64][32000] = h_final @ Why^T + Why_b.  250 WGs x [64 x 128] tile.
__global__ __launch_bounds__(NTHREADS) void rnn_proj(
    const unsigned short* __restrict__ hfin, const float* __restrict__ Why_w,
    const float* __restrict__ Why_b, float* __restrict__ out) {
  const int tid = threadIdx.x;
  const int w = tid >> 6;
  const int l = tid & 63;
  const int lr = l & 15;
  const int lq = l >> 4;
  const int nbase = blockIdx.x * 128;
  const int rowbase = w * 16;

  f32x4 acc[8];
  #pragma unroll
  for (int nt = 0; nt < 8; ++nt) acc[nt] = (f32x4){0.f, 0.f, 0.f, 0.f};

  const unsigned short* aptr = hfin + (size_t)(rowbase + lr) * HH + lq * 8;
  for (int kb = 0; kb < 32; ++kb) {
    s16x8 a = *reinterpret_cast<const s16x8*>(aptr + kb * 32);
    #pragma unroll
    for (int nt = 0; nt < 8; ++nt) {
      int n = nbase + nt * 16 + lr;
      const float* wp = Why_w + (size_t)n * HH + kb * 32 + lq * 8;
      union { unsigned short u[8]; s16x8 v; } bb;
      #pragma unroll
      for (int j = 0; j < 8; ++j) bb.u[j] = f2bf(wp[j]);
      acc[nt] = __builtin_amdgcn_mfma_f32_16x16x32_bf16(a, bb.v, acc[nt], 0, 0, 0);
    }
  }
  #pragma unroll
  for (int nt = 0; nt < 8; ++nt) {
    int n = nbase + nt * 16 + lr;
    float bv = Why_b[n];
    #pragma unroll
    for (int i = 0; i < 4; ++i) {
      int b = rowbase + lq * 4 + i;
      out[(size_t)b * OUTN + n] = acc[nt][i] + bv;
    }
  }
}

extern "C" void kernel_launch(void* const* d_in, const int* in_sizes, int n_in,
                              void* d_out, int out_size, void* d_ws, size_t ws_size,
                              hipStream_t stream) {
  const int* x = (const int*)d_in[0];
  const float* Wxh = (const float*)d_in[1];
  const float* Whh_w = (const float*)d_in[2];
  const float* Whh_b = (const float*)d_in[3];
  const float* Why_w = (const float*)d_in[4];
  const float* Why_b = (const float*)d_in[5];
  float* out = (float*)d_out;

  unsigned* flags = (unsigned*)d_ws;                                  // 512*32*4 = 64 KB
  unsigned short* hbuf = (unsigned short*)((char*)d_ws + TT * NG * 4); // 2 x 64 x 1024 bf16

  // zero flags + both h buffers each call — deterministic across replays
  hipMemsetAsync(d_ws, 0, TT * NG * 4 + 2 * BB * HH * sizeof(unsigned short), stream);
  rnn_persist<<<NG, NTHREADS, 0, stream>>>(x, Wxh, Whh_w, Whh_b, flags, hbuf);
  rnn_proj<<<OUTN / 128, NTHREADS, 0, stream>>>(hbuf, Why_w, Why_b, out);
}

// Round 3
// 2174.949 us; speedup vs baseline: 3.1914x; 1.7171x over previous
//
#include <hip/hip_runtime.h>

#define BB 64
#define TT 512
#define HH 1024
#define OUTN 32000
#define NGROUP 4            // independent batch row-groups (16 rows each)
#define NCB 32              // col-blocks per group (32 cols each)
#define NWG (NGROUP * NCB)  // 128 workgroups
#define NTH 128             // 2 waves per WG (one 16x16 col-tile each)

#define FLAGS_WORDS (TT * NGROUP * 32)   // [s][group][32] - each group = one 128B line
#define HBUF_OFF (FLAGS_WORDS * 4)
#define HBUF_BYTES (BB * HH * 2)         // 128 KB per buffer

typedef __attribute__((ext_vector_type(8))) short s16x8;
typedef __attribute__((ext_vector_type(4))) float f32x4;
typedef __attribute__((ext_vector_type(4))) int i32x4;

static __device__ __forceinline__ unsigned short f2bf(float f) {
  union { float f; unsigned u; } a; a.f = f;
  unsigned r = a.u + 0x7fffu + ((a.u >> 16) & 1u);   // RNE
  return (unsigned short)(r >> 16);
}

static __device__ __forceinline__ float ftanh(float x) {
  float e = __expf(2.0f * x);
  return 1.0f - 2.0f * __builtin_amdgcn_rcpf(e + 1.0f);
}

#define ALOAD(d, off_lit)                                              \
  asm volatile("global_load_dwordx4 %0, %1, %2 offset:" #off_lit       \
               " sc0 sc1"                                              \
               : "=v"(d) : "v"(vg), "s"(hprev) : "memory")

// h layout per buffer: [group 0..3][kb 0..31][row 0..15][col 0..31] bf16
// WG (group, cblk) writes block kb=cblk of its group: 1 KB contiguous.
__global__ __launch_bounds__(NTH, 1) void rnn_persist(
    const int* __restrict__ x, const float* __restrict__ Wxh,
    const float* __restrict__ Whh_w, const float* __restrict__ Whh_b,
    unsigned* __restrict__ flags, char* __restrict__ hbuf) {
  const int g = blockIdx.x;
  const int group = g >> 5;        // 0..3 -> batch rows [16*group, +16)
  const int cblk = g & 31;         // 0..31 -> cols [32*cblk, +32)
  const int tid = threadIdx.x;
  const int wv = tid >> 6;         // wave 0/1 -> col-tile
  const int l = tid & 63;
  const int lr = l & 15;
  const int lq = l >> 4;

  __shared__ __align__(16) unsigned short wlds[32 * 2 * 64 * 8];  // 64 KB B-frags
  __shared__ __align__(16) unsigned short epi[16 * 32];           // 1 KB repack

  // One-time B pack: lane ln supplies col = cblk*32 + nt*16 + (ln&15),
  // k = kb*32 + (ln>>4)*8 + j
  for (int e = tid; e < 32 * 2 * 64; e += NTH) {
    int kb = e >> 7;
    int nt = (e >> 6) & 1;
    int ln = e & 63;
    int col = cblk * 32 + nt * 16 + (ln & 15);
    int k0 = kb * 32 + (ln >> 4) * 8;
    const float* src = Whh_w + (size_t)col * HH + k0;
    union { unsigned short u[8]; i32x4 v; } pk;
    #pragma unroll
    for (int j = 0; j < 8; ++j) pk.u[j] = f2bf(src[j]);
    *reinterpret_cast<i32x4*>(&wlds[(size_t)e * 8]) = pk.v;
  }
  const int mycol = cblk * 32 + wv * 16 + lr;
  const float bias = Whh_b[mycol];
  __syncthreads();

  // prologue: x for step 0 (per lane: 4 batch rows lq*4+i of this group)
  int xv[4];
  #pragma unroll
  for (int i = 0; i < 4; ++i) xv[i] = x[(group * 16 + lq * 4 + i) * TT];

  for (int s = 0; s < TT; ++s) {
    const char* hprev = hbuf + (s & 1) * HBUF_BYTES + group * 32768;
    char* hcur = hbuf + ((s + 1) & 1) * HBUF_BYTES;

    // 1. poll this group's 32 flags for step s-1 (one coalesced line read)
    if (s > 0) {
      const unsigned* fp = flags + ((size_t)(s - 1) * NGROUP + group) * 32 + (l & 31);
      int guard = 0;
      unsigned fv;
      do {
        asm volatile("global_load_dword %0, %1, off sc0 sc1\n\t"
                     "s_waitcnt vmcnt(0)"
                     : "=v"(fv) : "v"(fp) : "memory");
        if (++guard > (1 << 15)) break;   // safety valve
      } while (!__all(fv != 0));
      __builtin_amdgcn_sched_barrier(0);
    }

    // 2. embedding gather for this step (xv from previous tail; latency
    //    covered by the A-stream below)
    float ev[4];
    #pragma unroll
    for (int i = 0; i < 4; ++i) ev[i] = Wxh[(size_t)xv[i] * HH + mycol];

    // 3. A-fragments: 32 line-coalesced 1KB block reads (lane-permuted)
    //    lane l: row lr, k-chunk lq -> byte kb*1024 + lr*64 + lq*16
    i32x4 areg[32];
    {
      unsigned voff = (unsigned)(lr * 64 + lq * 16);
      #pragma unroll
      for (int kg = 0; kg < 8; ++kg) {
        unsigned vg = voff + kg * 4096;
        ALOAD(areg[kg * 4 + 0], 0);
        ALOAD(areg[kg * 4 + 1], 1024);
        ALOAD(areg[kg * 4 + 2], 2048);
        ALOAD(areg[kg * 4 + 3], 3072);
      }
    }
    asm volatile("s_waitcnt vmcnt(0)" ::: "memory");
    __builtin_amdgcn_sched_barrier(0);

    // 4. 32 MFMA, 4 independent chains
    f32x4 ac[4];
    #pragma unroll
    for (int c = 0; c < 4; ++c) ac[c] = (f32x4){0.f, 0.f, 0.f, 0.f};
    #pragma unroll
    for (int kb = 0; kb < 32; ++kb) {
      union { i32x4 i; s16x8 s; } a;
      a.i = areg[kb];
      s16x8 b = *reinterpret_cast<const s16x8*>(&wlds[((kb * 2 + wv) * 64 + l) * 8]);
      ac[kb & 3] = __builtin_amdgcn_mfma_f32_16x16x32_bf16(a.s, b, ac[kb & 3], 0, 0, 0);
    }
    f32x4 acc = (ac[0] + ac[1]) + (ac[2] + ac[3]);

    // 5. tail: x loads for next step (cheap, L2-hot, hidden across barrier)
    if (s + 1 < TT) {
      #pragma unroll
      for (int i = 0; i < 4; ++i) xv[i] = x[(group * 16 + lq * 4 + i) * TT + s + 1];
    }

    // 6. epilogue -> LDS repack buffer (C/D: col=lane&15, row=(lane>>4)*4+i)
    #pragma unroll
    for (int i = 0; i < 4; ++i) {
      float v = ftanh(acc[i] + ev[i] + bias);
      epi[(lq * 4 + i) * 32 + wv * 16 + lr] = f2bf(v);
    }
    __syncthreads();

    // 7. one contiguous 1KB block store (64 threads x dwordx4), coherent
    if (tid < 64) {
      i32x4 vdat = *reinterpret_cast<const i32x4*>(&epi[tid * 8]);
      char* dst = hcur + (size_t)(group * 32 + cblk) * 1024 + tid * 16;
      asm volatile("global_store_dwordx4 %0, %1, off sc0 sc1"
                   :: "v"(dst), "v"(vdat) : "memory");
      asm volatile("s_waitcnt vmcnt(0)" ::: "memory");
    }
    __syncthreads();

    // 8. flag: this WG's block is visible at the coherence point
    if (tid == 0) {
      unsigned one = 1u;
      unsigned* fs = flags + ((size_t)s * NGROUP + group) * 32 + cblk;
      asm volatile("global_store_dword %0, %1, off sc0 sc1"
                   :: "v"(fs), "v"(one) : "memory");
    }
  }
}

// out[64][32000] = h_final @ Why^T + Why_b, reading block-layout h (buf 0).
__global__ __launch_bounds__(256) void rnn_proj(
    const char* __restrict__ hfin, const float* __restrict__ Why_w,
    const float* __restrict__ Why_b, float* __restrict__ out) {
  const int tid = threadIdx.x;
  const int w = tid >> 6;          // wave w -> group w (rows 16w..16w+16)
  const int l = tid & 63;
  const int lr = l & 15;
  const int lq = l >> 4;
  const int nbase = blockIdx.x * 128;

  f32x4 acc[8];
  #pragma unroll
  for (int nt = 0; nt < 8; ++nt) acc[nt] = (f32x4){0.f, 0.f, 0.f, 0.f};

  for (int kb = 0; kb < 32; ++kb) {
    s16x8 a = *reinterpret_cast<const s16x8*>(
        hfin + (size_t)((w * 32 + kb) * 16 + lr) * 64 + lq * 16);
    #pragma unroll
    for (int nt = 0; nt < 8; ++nt) {
      int n = nbase + nt * 16 + lr;
      const float* wp = Why_w + (size_t)n * HH + kb * 32 + lq * 8;
      union { unsigned short u[8]; s16x8 v; } bb;
      #pragma unroll
      for (int j = 0; j < 8; ++j) bb.u[j] = f2bf(wp[j]);
      acc[nt] = __builtin_amdgcn_mfma_f32_16x16x32_bf16(a, bb.v, acc[nt], 0, 0, 0);
    }
  }
  #pragma unroll
  for (int nt = 0; nt < 8; ++nt) {
    int n = nbase + nt * 16 + lr;
    float bv = Why_b[n];
    #pragma unroll
    for (int i = 0; i < 4; ++i) {
      int b = w * 16 + lq * 4 + i;
      out[(size_t)b * OUTN + n] = acc[nt][i] + bv;
    }
  }
}

extern "C" void kernel_launch(void* const* d_in, const int* in_sizes, int n_in,
                              void* d_out, int out_size, void* d_ws, size_t ws_size,
                              hipStream_t stream) {
  const int* x = (const int*)d_in[0];
  const float* Wxh = (const float*)d_in[1];
  const float* Whh_w = (const float*)d_in[2];
  const float* Whh_b = (const float*)d_in[3];
  const float* Why_w = (const float*)d_in[4];
  const float* Why_b = (const float*)d_in[5];
  float* out = (float*)d_out;

  unsigned* flags = (unsigned*)d_ws;
  char* hbuf = (char*)d_ws + HBUF_OFF;

  // zero flags + both h buffers each call — deterministic across replays
  hipMemsetAsync(d_ws, 0, HBUF_OFF + 2 * HBUF_BYTES, stream);
  rnn_persist<<<NWG, NTH, 0, stream>>>(x, Wxh, Whh_w, Whh_b, flags, hbuf);
  // final h is in buffer 0 (TT even)
  rnn_proj<<<OUTN / 128, 256, 0, stream>>>(hbuf, Why_w, Why_b, out);
}

// Round 5
// 1734.982 us; speedup vs baseline: 4.0007x; 1.2536x over previous
//
#include <hip/hip_runtime.h>

#define BB 64
#define TT 512
#define HH 1024
#define OUTN 32000
#define NDOM 4              // 4 independent domains: 16 batch rows each
#define NCB 32              // col-blocks per domain (32 cols each)
#define NWG (NDOM * NCB)    // 128 workgroups
#define NTH 128             // 2 waves: wave wv owns 16 of the WG's 32 cols
#define SLOT (BB * HH * 2)  // 128 KB per ring slot
// ring of 3 slots; slot layout: [dom 0..3][kb 0..31][row 0..15][col 0..31] bf16
// chunk = 16 B = (row, 8 cols); stored by ONE lane's dwordx4 (atomic unit);
// bit14 of the chunk's first u16 carries the step-phase (tanh => bit14==0).

typedef __attribute__((ext_vector_type(8))) short s16x8;
typedef __attribute__((ext_vector_type(4))) float f32x4;
typedef __attribute__((ext_vector_type(4))) int i32x4;

static __device__ __forceinline__ unsigned short f2bf(float f) {
  union { float f; unsigned u; } a; a.f = f;
  unsigned r = a.u + 0x7fffu + ((a.u >> 16) & 1u);   // RNE
  return (unsigned short)(r >> 16);
}

static __device__ __forceinline__ float ftanh(float x) {
  float e = __expf(2.0f * x);          // never NaN: inf -> 1, 0 -> -1 path ok
  return 1.0f - 2.0f * __builtin_amdgcn_rcpf(e + 1.0f);
}

// device-scope (agent) load: bypass L1+L2, hit the coherent point
#define ALD(idx, off_lit, vov)                                            \
  asm volatile("global_load_dwordx4 %0, %1, %2 offset:" #off_lit " sc1"   \
               : "=v"(areg[idx]) : "v"(vov), "s"(hprev) : "memory")

__global__ __launch_bounds__(NTH, 1) void rnn_persist(
    const int* __restrict__ x, const float* __restrict__ Wxh,
    const float* __restrict__ Whh_w, const float* __restrict__ Whh_b,
    char* __restrict__ hbuf) {
  const int g = blockIdx.x;
  const int dom = g >> 5;          // batch rows [16*dom, +16)
  const int cb = g & 31;           // cols [32*cb, +32)
  const int tid = threadIdx.x;
  const int wv = tid >> 6;
  const int l = tid & 63;
  const int lr = l & 15;
  const int lq = l >> 4;

  __shared__ __align__(16) unsigned short wlds[32 * 2 * 64 * 8];  // 64 KB B-frags
  __shared__ __align__(16) unsigned short epi[16 * 32];           // 1 KB repack

  // One-time B pack: lane ln supplies col = cb*32 + nt*16 + (ln&15),
  // k = kb*32 + (ln>>4)*8 + j  (MFMA B-fragment order)
  for (int e = tid; e < 32 * 2 * 64; e += NTH) {
    int kb = e >> 7;
    int nt = (e >> 6) & 1;
    int ln = e & 63;
    int col = cb * 32 + nt * 16 + (ln & 15);
    int k0 = kb * 32 + (ln >> 4) * 8;
    const float* src = Whh_w + (size_t)col * HH + k0;
    union { unsigned short u[8]; i32x4 v; } pk;
    #pragma unroll
    for (int j = 0; j < 8; ++j) pk.u[j] = f2bf(src[j]);
    *reinterpret_cast<i32x4*>(&wlds[(size_t)e * 8]) = pk.v;
  }
  const int mycol = cb * 32 + wv * 16 + lr;
  const float bias = Whh_b[mycol];
  __syncthreads();

  // x row bases + step-0 tokens (per lane: 4 batch rows lq*4+i of this domain)
  int xrow[4], xv[4];
  #pragma unroll
  for (int i = 0; i < 4; ++i) {
    xrow[i] = (dom * 16 + lq * 4 + i) * TT;
    xv[i] = x[xrow[i]];
  }

  // per-lane A-chunk offset within the domain slice: row lr, colgroup lq
  const unsigned vo0 = (unsigned)(lr * 64 + lq * 16);
  const unsigned vo1 = vo0 + 4096, vo2 = vo0 + 8192, vo3 = vo0 + 12288;
  const unsigned vo4 = vo0 + 16384, vo5 = vo0 + 20480, vo6 = vo0 + 24576,
                 vo7 = vo0 + 28672;

  for (int s = 0; s < TT; ++s) {
    const char* hprev = hbuf + (s % 3) * SLOT + dom * 32768;
    char* hcur = hbuf + ((s + 1) % 3) * SLOT + dom * 32768;

    // embedding gather — plain cached loads, issued before the poll so the
    // HBM latency hides under the poll round trip
    float ev[4];
    #pragma unroll
    for (int i = 0; i < 4; ++i) ev[i] = Wxh[(size_t)xv[i] * HH + mycol];

    // poll-and-load: the A-data IS the ready flag (phase bit14 of each chunk)
    i32x4 areg[32];
    const unsigned want = (unsigned)(s & 1) << 14;
    int guard = 0;
    for (;;) {
      ALD(0, 0, vo0);    ALD(1, 1024, vo0);  ALD(2, 2048, vo0);  ALD(3, 3072, vo0);
      ALD(4, 0, vo1);    ALD(5, 1024, vo1);  ALD(6, 2048, vo1);  ALD(7, 3072, vo1);
      ALD(8, 0, vo2);    ALD(9, 1024, vo2);  ALD(10, 2048, vo2); ALD(11, 3072, vo2);
      ALD(12, 0, vo3);   ALD(13, 1024, vo3); ALD(14, 2048, vo3); ALD(15, 3072, vo3);
      ALD(16, 0, vo4);   ALD(17, 1024, vo4); ALD(18, 2048, vo4); ALD(19, 3072, vo4);
      ALD(20, 0, vo5);   ALD(21, 1024, vo5); ALD(22, 2048, vo5); ALD(23, 3072, vo5);
      ALD(24, 0, vo6);   ALD(25, 1024, vo6); ALD(26, 2048, vo6); ALD(27, 3072, vo6);
      ALD(28, 0, vo7);   ALD(29, 1024, vo7); ALD(30, 2048, vo7); ALD(31, 3072, vo7);
      asm volatile("s_waitcnt vmcnt(0)" ::: "memory");
      __builtin_amdgcn_sched_barrier(0);
      unsigned bad = 0;
      #pragma unroll
      for (int kb = 0; kb < 32; ++kb)
        bad |= (((unsigned)areg[kb][0]) ^ want) & 0x4000u;
      if (__all(bad == 0)) break;
      if (++guard > (1 << 17)) break;   // safety valve: never hard-wedge
    }
    // clear the phase bit (data bit14 is always 0 for tanh outputs)
    #pragma unroll
    for (int kb = 0; kb < 32; ++kb) areg[kb][0] &= ~0x4000;

    // prefetch next step's tokens (L2-hot)
    if (s + 1 < TT) {
      #pragma unroll
      for (int i = 0; i < 4; ++i) xv[i] = x[xrow[i] + s + 1];
    }

    // 32 MFMA, 4 independent chains
    f32x4 ac[4];
    #pragma unroll
    for (int c = 0; c < 4; ++c) ac[c] = (f32x4){0.f, 0.f, 0.f, 0.f};
    #pragma unroll
    for (int kb = 0; kb < 32; ++kb) {
      union { i32x4 i; s16x8 s; } a;
      a.i = areg[kb];
      s16x8 b = *reinterpret_cast<const s16x8*>(&wlds[((kb * 2 + wv) * 64 + l) * 8]);
      ac[kb & 3] = __builtin_amdgcn_mfma_f32_16x16x32_bf16(a.s, b, ac[kb & 3], 0, 0, 0);
    }
    f32x4 acc = (ac[0] + ac[1]) + (ac[2] + ac[3]);

    // epilogue: C/D col=lane&15, row=(lane>>4)*4+i -> LDS repack [row][col]
    #pragma unroll
    for (int i = 0; i < 4; ++i) {
      float v = ftanh(acc[i] + ev[i] + bias);
      epi[(lq * 4 + i) * 32 + wv * 16 + lr] = f2bf(v);
    }
    __syncthreads();

    // store the 1 KB block as 64 x 16B chunks, phase bit set in each chunk.
    // wave1's next poll can't pass until this store lands (own block), so no
    // second barrier is needed before the next epi overwrite.
    if (tid < 64) {
      i32x4 v = *reinterpret_cast<const i32x4*>(&epi[tid * 8]);
      v[0] |= (int)(((unsigned)((s + 1) & 1)) << 14);
      char* dst = hcur + cb * 1024 + tid * 16;
      asm volatile("global_store_dwordx4 %0, %1, off sc1"
                   :: "v"(dst), "v"(v) : "memory");
    }
  }
}

// out[64][32000] = h_final @ Why^T + Why_b; h_512 lives in ring slot 2
// (512 % 3 == 2) with phase bit (512&1)==0 -> data is clean, no fixup.
__global__ __launch_bounds__(256) void rnn_proj(
    const char* __restrict__ hfin, const float* __restrict__ Why_w,
    const float* __restrict__ Why_b, float* __restrict__ out) {
  const int tid = threadIdx.x;
  const int w = tid >> 6;
  const int l = tid & 63;
  const int lr = l & 15;
  const int lq = l >> 4;
  const int nbase = blockIdx.x * 128;
  const int row = w * 16 + lr;

  f32x4 acc[8];
  #pragma unroll
  for (int nt = 0; nt < 8; ++nt) acc[nt] = (f32x4){0.f, 0.f, 0.f, 0.f};

  const char* abase = hfin + (size_t)(row >> 4) * 32768 + (row & 15) * 64 + lq * 16;
  for (int kb = 0; kb < 32; ++kb) {
    s16x8 a = *reinterpret_cast<const s16x8*>(abase + kb * 1024);
    #pragma unroll
    for (int nt = 0; nt < 8; ++nt) {
      int n = nbase + nt * 16 + lr;
      const float* wp = Why_w + (size_t)n * HH + kb * 32 + lq * 8;
      union { unsigned short u[8]; s16x8 v; } bb;
      #pragma unroll
      for (int j = 0; j < 8; ++j) bb.u[j] = f2bf(wp[j]);
      acc[nt] = __builtin_amdgcn_mfma_f32_16x16x32_bf16(a, bb.v, acc[nt], 0, 0, 0);
    }
  }
  #pragma unroll
  for (int nt = 0; nt < 8; ++nt) {
    int n = nbase + nt * 16 + lr;
    float bv = Why_b[n];
    #pragma unroll
    for (int i = 0; i < 4; ++i) {
      int b = w * 16 + lq * 4 + i;
      out[(size_t)b * OUTN + n] = acc[nt][i] + bv;
    }
  }
}

extern "C" void kernel_launch(void* const* d_in, const int* in_sizes, int n_in,
                              void* d_out, int out_size, void* d_ws, size_t ws_size,
                              hipStream_t stream) {
  const int* x = (const int*)d_in[0];
  const float* Wxh = (const float*)d_in[1];
  const float* Whh_w = (const float*)d_in[2];
  const float* Whh_b = (const float*)d_in[3];
  const float* Why_w = (const float*)d_in[4];
  const float* Why_b = (const float*)d_in[5];
  float* out = (float*)d_out;

  char* hbuf = (char*)d_ws;   // 3 ring slots x 128 KB = 384 KB

  // slot0 = h_0 = zeros (phase 0 valid); slot1 = 0x00 (bit14=0 != phase 1);
  // slot2 = 0x40 (bit14=1 != phase 0). Re-done every call — deterministic.
  hipMemsetAsync(hbuf, 0x00, 2 * SLOT, stream);
  hipMemsetAsync(hbuf + 2 * SLOT, 0x40, SLOT, stream);
  rnn_persist<<<NWG, NTH, 0, stream>>>(x, Wxh, Whh_w, Whh_b, hbuf);
  rnn_proj<<<OUTN / 128, 256, 0, stream>>>(hbuf + 2 * SLOT, Why_w, Why_b, out);
}

// Round 6
// 1685.566 us; speedup vs baseline: 4.1180x; 1.0293x over previous
//
#include <hip/hip_runtime.h>

#define BB 64
#define TT 512
#define HH 1024
#define OUTN 32000
#define NDOM 4              // 4 independent domains: 16 batch rows each
#define NCB 32              // col-blocks per domain (32 cols each)
#define NWG (NDOM * NCB)    // 128 workgroups
#define NTH 128             // 2 waves: wave wv owns 16 of the WG's 32 cols
#define SLOT (BB * HH * 2)  // 128 KB per ring slot
#define FLAGS_BYTES 4096
// ws: [flags 4KB][ring of 3 slots x 128 KB]
// slot layout: [dom 0..3][kb 0..31][row 0..15][col 0..31] bf16
// chunk = 16 B = (row, 8 cols), one lane's dwordx4 (atomic unit);
// bit14 of chunk's first u16 = step phase (tanh output => bit14 is 0).
// flags[dom*32+cb] = monotonic step counter (s+1 stored after h_{s+1} block).

typedef __attribute__((ext_vector_type(8))) short s16x8;
typedef __attribute__((ext_vector_type(4))) float f32x4;
typedef __attribute__((ext_vector_type(4))) int i32x4;

static __device__ __forceinline__ unsigned short f2bf(float f) {
  union { float f; unsigned u; } a; a.f = f;
  unsigned r = a.u + 0x7fffu + ((a.u >> 16) & 1u);   // RNE
  return (unsigned short)(r >> 16);
}

static __device__ __forceinline__ float ftanh(float x) {
  float e = __expf(2.0f * x);
  return 1.0f - 2.0f * __builtin_amdgcn_rcpf(e + 1.0f);
}

// device-scope load, bypasses non-coherent tiers
#define ALD(idx, off_lit, vov)                                            \
  asm volatile("global_load_dwordx4 %0, %1, %2 offset:" #off_lit " sc1"   \
               : "=v"(areg[idx]) : "v"(vov), "s"(hprev) : "memory")

__global__ __launch_bounds__(NTH, 1) void rnn_persist(
    const int* __restrict__ x, const float* __restrict__ Wxh,
    const float* __restrict__ Whh_w, const float* __restrict__ Whh_b,
    unsigned* __restrict__ flags, char* __restrict__ hbuf) {
  const int g = blockIdx.x;
  const int dom = g >> 5;          // batch rows [16*dom, +16)
  const int cb = g & 31;           // cols [32*cb, +32)
  const int tid = threadIdx.x;
  const int wv = tid >> 6;
  const int l = tid & 63;
  const int lr = l & 15;
  const int lq = l >> 4;

  __shared__ __align__(16) unsigned short wlds[32 * 2 * 64 * 8];  // 64 KB B-frags
  __shared__ __align__(16) unsigned short epi[16 * 32];           // 1 KB repack

  // One-time B pack (MFMA B-fragment order)
  for (int e = tid; e < 32 * 2 * 64; e += NTH) {
    int kb = e >> 7;
    int nt = (e >> 6) & 1;
    int ln = e & 63;
    int col = cb * 32 + nt * 16 + (ln & 15);
    int k0 = kb * 32 + (ln >> 4) * 8;
    const float* src = Whh_w + (size_t)col * HH + k0;
    union { unsigned short u[8]; i32x4 v; } pk;
    #pragma unroll
    for (int j = 0; j < 8; ++j) pk.u[j] = f2bf(src[j]);
    *reinterpret_cast<i32x4*>(&wlds[(size_t)e * 8]) = pk.v;
  }
  const int mycol = cb * 32 + wv * 16 + lr;
  const float bias = Whh_b[mycol];
  __syncthreads();

  int xrow[4], xv[4];
  #pragma unroll
  for (int i = 0; i < 4; ++i) {
    xrow[i] = (dom * 16 + lq * 4 + i) * TT;
    xv[i] = x[xrow[i]];
  }

  const unsigned* flagsD = flags + dom * 32;
  const unsigned vo0 = (unsigned)(lr * 64 + lq * 16);
  const unsigned vo1 = vo0 + 4096, vo2 = vo0 + 8192, vo3 = vo0 + 12288;
  const unsigned vo4 = vo0 + 16384, vo5 = vo0 + 20480, vo6 = vo0 + 24576,
                 vo7 = vo0 + 28672;

  for (int s = 0; s < TT; ++s) {
    const char* hprev = hbuf + (s % 3) * SLOT + dom * 32768;
    char* hcur = hbuf + ((s + 1) % 3) * SLOT + dom * 32768;

    // embedding gather — cached, latency hides under the poll
    float ev[4];
    #pragma unroll
    for (int i = 0; i < 4; ++i) ev[i] = Wxh[(size_t)xv[i] * HH + mycol];

    // 1. cheap readiness poll: 32 flag dwords (128 B) per iteration
    if (s > 0) {
      const unsigned* fp = flagsD + (l & 31);
      int guard = 0;
      unsigned fv;
      do {
        asm volatile("global_load_dword %0, %1, off sc1\n\t"
                     "s_waitcnt vmcnt(0)"
                     : "=v"(fv) : "v"(fp) : "memory");
        if (++guard > (1 << 17)) break;   // safety valve
      } while (!__all(fv >= (unsigned)s));
      __builtin_amdgcn_sched_barrier(0);
    }

    // 2. one-shot A-load + phase-bit verify (reloads only on the rare race)
    i32x4 areg[32];
    const unsigned want = (unsigned)(s & 1) << 14;
    int guard2 = 0;
    for (;;) {
      ALD(0, 0, vo0);    ALD(1, 1024, vo0);  ALD(2, 2048, vo0);  ALD(3, 3072, vo0);
      ALD(4, 0, vo1);    ALD(5, 1024, vo1);  ALD(6, 2048, vo1);  ALD(7, 3072, vo1);
      ALD(8, 0, vo2);    ALD(9, 1024, vo2);  ALD(10, 2048, vo2); ALD(11, 3072, vo2);
      ALD(12, 0, vo3);   ALD(13, 1024, vo3); ALD(14, 2048, vo3); ALD(15, 3072, vo3);
      ALD(16, 0, vo4);   ALD(17, 1024, vo4); ALD(18, 2048, vo4); ALD(19, 3072, vo4);
      ALD(20, 0, vo5);   ALD(21, 1024, vo5); ALD(22, 2048, vo5); ALD(23, 3072, vo5);
      ALD(24, 0, vo6);   ALD(25, 1024, vo6); ALD(26, 2048, vo6); ALD(27, 3072, vo6);
      ALD(28, 0, vo7);   ALD(29, 1024, vo7); ALD(30, 2048, vo7); ALD(31, 3072, vo7);
      asm volatile("s_waitcnt vmcnt(0)" ::: "memory");
      __builtin_amdgcn_sched_barrier(0);
      unsigned bad = 0;
      #pragma unroll
      for (int kb = 0; kb < 32; ++kb)
        bad |= (((unsigned)areg[kb][0]) ^ want) & 0x4000u;
      if (__all(bad == 0)) break;
      if (++guard2 > (1 << 17)) break;   // safety valve
    }
    #pragma unroll
    for (int kb = 0; kb < 32; ++kb) areg[kb][0] &= ~0x4000;  // clear phase bit

    // prefetch next step's tokens (L2-hot)
    if (s + 1 < TT) {
      #pragma unroll
      for (int i = 0; i < 4; ++i) xv[i] = x[xrow[i] + s + 1];
    }

    // 3. 32 MFMA, 4 independent chains
    f32x4 ac[4];
    #pragma unroll
    for (int c = 0; c < 4; ++c) ac[c] = (f32x4){0.f, 0.f, 0.f, 0.f};
    #pragma unroll
    for (int kb = 0; kb < 32; ++kb) {
      union { i32x4 i; s16x8 s; } a;
      a.i = areg[kb];
      s16x8 b = *reinterpret_cast<const s16x8*>(&wlds[((kb * 2 + wv) * 64 + l) * 8]);
      ac[kb & 3] = __builtin_amdgcn_mfma_f32_16x16x32_bf16(a.s, b, ac[kb & 3], 0, 0, 0);
    }
    f32x4 acc = (ac[0] + ac[1]) + (ac[2] + ac[3]);

    // 4. epilogue: C/D col=lane&15, row=(lane>>4)*4+i -> LDS repack [row][col]
    #pragma unroll
    for (int i = 0; i < 4; ++i) {
      float v = ftanh(acc[i] + ev[i] + bias);
      epi[(lq * 4 + i) * 32 + wv * 16 + lr] = f2bf(v);
    }
    __syncthreads();

    // 5. wave0: one wave-wide 1KB block store (phase-tagged chunks), then
    //    the block flag — issued immediately (no vmcnt); consumers verify.
    if (tid < 64) {
      i32x4 v = *reinterpret_cast<const i32x4*>(&epi[tid * 8]);
      v[0] |= (int)(((unsigned)((s + 1) & 1)) << 14);
      char* dst = hcur + cb * 1024 + tid * 16;
      asm volatile("global_store_dwordx4 %0, %1, off sc1"
                   :: "v"(dst), "v"(v) : "memory");
      if (tid == 0) {
        unsigned sv = (unsigned)(s + 1);
        asm volatile("global_store_dword %0, %1, off sc1"
                     :: "v"(flagsD + cb), "v"(sv) : "memory");
      }
    }
  }
}

// out[64][32000] = h_final @ Why^T + Why_b; h_512 = ring slot 2, phase 0 clean.
__global__ __launch_bounds__(256) void rnn_proj(
    const char* __restrict__ hfin, const float* __restrict__ Why_w,
    const float* __restrict__ Why_b, float* __restrict__ out) {
  const int tid = threadIdx.x;
  const int w = tid >> 6;
  const int l = tid & 63;
  const int lr = l & 15;
  const int lq = l >> 4;
  const int nbase = blockIdx.x * 128;
  const int row = w * 16 + lr;

  f32x4 acc[8];
  #pragma unroll
  for (int nt = 0; nt < 8; ++nt) acc[nt] = (f32x4){0.f, 0.f, 0.f, 0.f};

  const char* abase = hfin + (size_t)(row >> 4) * 32768 + (row & 15) * 64 + lq * 16;
  for (int kb = 0; kb < 32; ++kb) {
    s16x8 a = *reinterpret_cast<const s16x8*>(abase + kb * 1024);
    #pragma unroll
    for (int nt = 0; nt < 8; ++nt) {
      int n = nbase + nt * 16 + lr;
      const float* wp = Why_w + (size_t)n * HH + kb * 32 + lq * 8;
      union { unsigned short u[8]; s16x8 v; } bb;
      #pragma unroll
      for (int j = 0; j < 8; ++j) bb.u[j] = f2bf(wp[j]);
      acc[nt] = __builtin_amdgcn_mfma_f32_16x16x32_bf16(a, bb.v, acc[nt], 0, 0, 0);
    }
  }
  #pragma unroll
  for (int nt = 0; nt < 8; ++nt) {
    int n = nbase + nt * 16 + lr;
    float bv = Why_b[n];
    #pragma unroll
    for (int i = 0; i < 4; ++i) {
      int b = w * 16 + lq * 4 + i;
      out[(size_t)b * OUTN + n] = acc[nt][i] + bv;
    }
  }
}

extern "C" void kernel_launch(void* const* d_in, const int* in_sizes, int n_in,
                              void* d_out, int out_size, void* d_ws, size_t ws_size,
                              hipStream_t stream) {
  const int* x = (const int*)d_in[0];
  const float* Wxh = (const float*)d_in[1];
  const float* Whh_w = (const float*)d_in[2];
  const float* Whh_b = (const float*)d_in[3];
  const float* Why_w = (const float*)d_in[4];
  const float* Why_b = (const float*)d_in[5];
  float* out = (float*)d_out;

  unsigned* flags = (unsigned*)d_ws;
  char* hbuf = (char*)d_ws + FLAGS_BYTES;

  // flags=0; slot0 = h_0 = zeros (phase0 valid); slot1 = 0x00 (!=phase1);
  // slot2 = 0x40 (bit14=1 != phase0). Re-done every call — deterministic.
  hipMemsetAsync(d_ws, 0x00, FLAGS_BYTES + 2 * SLOT, stream);
  hipMemsetAsync(hbuf + 2 * SLOT, 0x40, SLOT, stream);
  rnn_persist<<<NWG, NTH, 0, stream>>>(x, Wxh, Whh_w, Whh_b, flags, hbuf);
  rnn_proj<<<OUTN / 128, 256, 0, stream>>>(hbuf + 2 * SLOT, Why_w, Why_b, out);
}